// Round 1
// baseline (106.266 us; speedup 1.0000x reference)
//
#include <hip/hip_runtime.h>

// EmbeddingShard: out[n, :] = (W_full[x[n], :] + sum_s b[s, :]) / SHARDS
//   x: int32 [8,2048] = 16384 tokens
//   W: fp32  [8, 6300, 4096] == contiguous [50400, 4096]
//   b: fp32  [8, 4096]
//   out: fp32 [16384, 4096]
// Memory-bound gather: ~230 MB read + 256 MB write.

#define IN_DIM   50400
#define OUT_DIM  4096
#define SHARDS   8
#define N_TOK    16384

// Kernel 1: bsum[j] = (1/SHARDS) * sum_s b[s][j]   (4096 floats into d_ws)
__global__ __launch_bounds__(256) void bias_sum_kernel(const float* __restrict__ b,
                                                       float* __restrict__ bsum) {
    int j = blockIdx.x * blockDim.x + threadIdx.x;
    if (j < OUT_DIM) {
        float s = 0.0f;
#pragma unroll
        for (int sd = 0; sd < SHARDS; ++sd) {
            s += b[sd * OUT_DIM + j];
        }
        bsum[j] = s * (1.0f / SHARDS);
    }
}

// Kernel 2: one block per token row; 256 threads x 4 float4 = 4096 floats/row.
__global__ __launch_bounds__(256) void gather_bias_kernel(const int* __restrict__ x,
                                                          const float* __restrict__ W,
                                                          const float* __restrict__ bsum,
                                                          float* __restrict__ out) {
    const int n = blockIdx.x;               // token index [0, 16384)
    const int row = x[n];                   // vocab row [0, 50400) — wave-uniform
    const float4* __restrict__ wrow = reinterpret_cast<const float4*>(W + (size_t)row * OUT_DIM);
    const float4* __restrict__ bs4  = reinterpret_cast<const float4*>(bsum);
    float4* __restrict__ orow       = reinterpret_cast<float4*>(out + (size_t)n * OUT_DIM);

#pragma unroll
    for (int i = 0; i < 4; ++i) {
        const int j = threadIdx.x + i * 256;     // [0, 1024) float4 slots
        const float4 w = wrow[j];
        const float4 bb = bs4[j];                // L1-resident (16 KB)
        float4 o;
        o.x = fmaf(w.x, 0.125f, bb.x);
        o.y = fmaf(w.y, 0.125f, bb.y);
        o.z = fmaf(w.z, 0.125f, bb.z);
        o.w = fmaf(w.w, 0.125f, bb.w);
        orow[j] = o;
    }
}

extern "C" void kernel_launch(void* const* d_in, const int* in_sizes, int n_in,
                              void* d_out, int out_size, void* d_ws, size_t ws_size,
                              hipStream_t stream) {
    const int*   x = (const int*)d_in[0];    // [16384]
    const float* W = (const float*)d_in[1];  // [50400*4096]
    const float* b = (const float*)d_in[2];  // [8*4096]
    float* out  = (float*)d_out;             // [16384*4096]
    float* bsum = (float*)d_ws;              // 4096 floats of scratch

    bias_sum_kernel<<<(OUT_DIM + 255) / 256, 256, 0, stream>>>(b, bsum);
    gather_bias_kernel<<<N_TOK, 256, 0, stream>>>(x, W, bsum, out);
}

// Round 3
// 98.605 us; speedup vs baseline: 1.0777x; 1.0777x over previous
//
#include <hip/hip_runtime.h>

// EmbeddingShard: out[n, :] = (W_full[x[n], :] + sum_s b[s, :]) / SHARDS
//   x: int32 [16384], W: fp32 [50400, 4096], b: fp32 [8, 4096]
//   out: fp32 [16384, 4096]
// Memory-bound gather: ~230 MB read + 256 MB write -> target ~80 us @ 6.3 TB/s.

#define IN_DIM   50400
#define OUT_DIM  4096
#define SHARDS   8
#define N_TOK    16384

#define BLOCKS   2048            // 8 blocks/CU resident (32 waves/CU = max occupancy)
#define THREADS  256
#define SLOTS4   (N_TOK * (OUT_DIM / 4))          // 16,777,216 float4 slots
#define NTHREADS (BLOCKS * THREADS)               // 524,288
#define ITERS    (SLOTS4 / NTHREADS)              // 32, exact
#define ROWSTEP  (NTHREADS / (OUT_DIM / 4))       // 512 rows per iteration step

typedef float f4 __attribute__((ext_vector_type(4)));   // clang-native: OK for nontemporal builtins

// Kernel 1: bsum[j] = (1/SHARDS) * sum_s b[s][j]   (4096 floats into d_ws)
__global__ __launch_bounds__(256) void bias_sum_kernel(const float* __restrict__ b,
                                                       float* __restrict__ bsum) {
    int j = blockIdx.x * blockDim.x + threadIdx.x;
    if (j < OUT_DIM) {
        float s = 0.0f;
#pragma unroll
        for (int sd = 0; sd < SHARDS; ++sd) s += b[sd * OUT_DIM + j];
        bsum[j] = s * (1.0f / SHARDS);
    }
}

// Kernel 2: persistent grid-stride gather. Each thread owns one float4 column j
// (bias in-register) and walks 32 token rows at stride 512.
__global__ __launch_bounds__(256) void gather_bias_kernel(const int* __restrict__ x,
                                                          const f4* __restrict__ W4,
                                                          const f4* __restrict__ bsum4,
                                                          f4* __restrict__ out4) {
    const int tid = blockIdx.x * THREADS + threadIdx.x;  // [0, 524288)
    const int j   = tid & (OUT_DIM / 4 - 1);             // float4 column, fixed
    const int n0  = tid >> 10;                           // starting token row
    const f4 bb = bsum4[j];                              // loaded once

#pragma unroll 4
    for (int it = 0; it < ITERS; ++it) {
        const int n   = n0 + it * ROWSTEP;               // token index
        const int row = x[n];                            // wave-uniform broadcast
        const f4 w = W4[(size_t)row * (OUT_DIM / 4) + j];
        f4 o;
        o.x = fmaf(w.x, 0.125f, bb.x);
        o.y = fmaf(w.y, 0.125f, bb.y);
        o.z = fmaf(w.z, 0.125f, bb.z);
        o.w = fmaf(w.w, 0.125f, bb.w);
        __builtin_nontemporal_store(o, &out4[(size_t)n * (OUT_DIM / 4) + j]);
    }
}

extern "C" void kernel_launch(void* const* d_in, const int* in_sizes, int n_in,
                              void* d_out, int out_size, void* d_ws, size_t ws_size,
                              hipStream_t stream) {
    const int*   x = (const int*)d_in[0];    // [16384]
    const float* W = (const float*)d_in[1];  // [50400*4096]
    const float* b = (const float*)d_in[2];  // [8*4096]
    float* out  = (float*)d_out;             // [16384*4096]
    float* bsum = (float*)d_ws;              // 4096 floats of scratch

    bias_sum_kernel<<<(OUT_DIM + 255) / 256, 256, 0, stream>>>(b, bsum);
    gather_bias_kernel<<<BLOCKS, THREADS, 0, stream>>>(
        x, (const f4*)W, (const f4*)bsum, (f4*)out);
}

// Round 4
// 98.373 us; speedup vs baseline: 1.0802x; 1.0024x over previous
//
#include <hip/hip_runtime.h>

// EmbeddingShard: out[n, :] = (W_full[x[n], :] + sum_s b[s, :]) / SHARDS
//   x: int32 [16384], W: fp32 [50400, 4096], b: fp32 [8, 4096]
//   out: fp32 [16384, 4096]
// Memory-bound gather: ~230 MB read + 256 MB write -> target ~80 us @ 6.3 TB/s.
// Structure: persistent grid, wave-uniform row index scalarized via
// readfirstlane so all 32 idx loads become up-front s_loads (SGPRs), and every
// gather is SGPR-base + uniform voffset. 8-deep unroll for MLP. Bias fused.

#define IN_DIM   50400
#define OUT_DIM  4096
#define SHARDS   8
#define N_TOK    16384

#define BLOCKS   2048            // 8 blocks/CU resident (32 waves/CU = max occupancy)
#define THREADS  256
#define SLOTS4   (N_TOK * (OUT_DIM / 4))          // 16,777,216 float4 slots
#define NTHREADS (BLOCKS * THREADS)               // 524,288
#define ITERS    (SLOTS4 / NTHREADS)              // 32, exact
#define ROWSTEP  (NTHREADS / (OUT_DIM / 4))       // 512 rows per iteration step

typedef float f4 __attribute__((ext_vector_type(4)));

__global__ __launch_bounds__(256) void gather_bias_kernel(const int* __restrict__ x,
                                                          const f4* __restrict__ W4,
                                                          const f4* __restrict__ b4,
                                                          f4* __restrict__ out4) {
    const int tid = blockIdx.x * THREADS + threadIdx.x;  // [0, 524288)
    const int j   = tid & (OUT_DIM / 4 - 1);             // float4 column, fixed
    // tid>>10 is constant across a 64-lane wave (waves are 64-aligned in tid);
    // force it into an SGPR so idx loads scalarize to s_load.
    const int n0  = __builtin_amdgcn_readfirstlane(tid >> 10);

    // Fused bias: bb = (1/SHARDS) * sum_s b[s][j]  (b is 128 KB, L2-resident)
    f4 bb = b4[j];
#pragma unroll
    for (int s = 1; s < SHARDS; ++s) bb += b4[s * (OUT_DIM / 4) + j];
    bb *= (1.0f / SHARDS);

    // All 32 row indices up front: uniform address -> s_load into SGPRs.
    int rows[ITERS];
#pragma unroll
    for (int it = 0; it < ITERS; ++it) rows[it] = x[n0 + it * ROWSTEP];

#pragma unroll 8
    for (int it = 0; it < ITERS; ++it) {
        const f4 w = W4[(size_t)rows[it] * (OUT_DIM / 4) + j];   // SGPR base + j*16
        f4 o = w * (1.0f / SHARDS) + bb;
        __builtin_nontemporal_store(
            o, &out4[(size_t)(n0 + it * ROWSTEP) * (OUT_DIM / 4) + j]);
    }
}

extern "C" void kernel_launch(void* const* d_in, const int* in_sizes, int n_in,
                              void* d_out, int out_size, void* d_ws, size_t ws_size,
                              hipStream_t stream) {
    const int*   x = (const int*)d_in[0];    // [16384]
    const float* W = (const float*)d_in[1];  // [50400*4096]
    const float* b = (const float*)d_in[2];  // [8*4096]
    float* out = (float*)d_out;              // [16384*4096]

    gather_bias_kernel<<<BLOCKS, THREADS, 0, stream>>>(
        x, (const f4*)W, (const f4*)b, (f4*)out);
}

// Round 5
// 96.342 us; speedup vs baseline: 1.1030x; 1.0211x over previous
//
#include <hip/hip_runtime.h>

// EmbeddingShard: out[n, :] = (W_full[x[n], :] + sum_s b[s, :]) / SHARDS
//   x: int32 [16384], W: fp32 [50400, 4096], b: fp32 [8, 4096]
//   out: fp32 [16384, 4096]
// Mapping: wave-owns-row. 8192 waves; each wave streams 2 full 16 KB rows
// (read W row -> scale+bias -> NT-store out row) as contiguous bursts for
// DRAM page locality. Bias presummed into d_ws (16 KB, L1-resident).

#define IN_DIM   50400
#define OUT_DIM  4096
#define SHARDS   8
#define N_TOK    16384

#define BLOCKS   2048            // 8 blocks/CU (32 waves/CU = max occupancy)
#define THREADS  256
#define NWAVES   (BLOCKS * THREADS / 64)   // 8192 -> 2 tokens per wave
#define SLOT4    (OUT_DIM / 4)             // 1024 float4 per row

typedef float f4 __attribute__((ext_vector_type(4)));

// Kernel 1: bsum[j] = (1/SHARDS) * sum_s b[s][j]  (4096 floats into d_ws)
__global__ __launch_bounds__(256) void bias_sum_kernel(const float* __restrict__ b,
                                                       float* __restrict__ bsum) {
    int j = blockIdx.x * blockDim.x + threadIdx.x;
    if (j < OUT_DIM) {
        float s = 0.0f;
#pragma unroll
        for (int sd = 0; sd < SHARDS; ++sd) s += b[sd * OUT_DIM + j];
        bsum[j] = s * (1.0f / SHARDS);
    }
}

// Kernel 2: each wave owns tokens {w, w+8192}; walks both 16 KB rows
// sequentially, 1 KB (64 lanes x 16 B) per iteration, interleaved for MLP.
__global__ __launch_bounds__(256) void gather_rows_kernel(const int* __restrict__ x,
                                                          const f4* __restrict__ W4,
                                                          const f4* __restrict__ bsum4,
                                                          f4* __restrict__ out4) {
    const int lane = threadIdx.x & 63;
    const int wv   = __builtin_amdgcn_readfirstlane((blockIdx.x * THREADS + threadIdx.x) >> 6);
    const int n0 = wv;                    // token 0
    const int n1 = wv + NWAVES;           // token 1
    const int r0 = x[n0];                 // uniform -> s_load
    const int r1 = x[n1];

    const f4* __restrict__ w0 = W4 + (size_t)r0 * SLOT4;
    const f4* __restrict__ w1 = W4 + (size_t)r1 * SLOT4;
    f4* __restrict__ o0 = out4 + (size_t)n0 * SLOT4;
    f4* __restrict__ o1 = out4 + (size_t)n1 * SLOT4;

#pragma unroll 4
    for (int it = 0; it < 16; ++it) {
        const int j = lane + it * 64;     // sequential 1 KB chunks per wave
        const f4 a  = w0[j];
        const f4 c  = w1[j];
        const f4 bb = bsum4[j];           // L1-resident (16 KB)
        __builtin_nontemporal_store(a * 0.125f + bb, &o0[j]);
        __builtin_nontemporal_store(c * 0.125f + bb, &o1[j]);
    }
}

extern "C" void kernel_launch(void* const* d_in, const int* in_sizes, int n_in,
                              void* d_out, int out_size, void* d_ws, size_t ws_size,
                              hipStream_t stream) {
    const int*   x = (const int*)d_in[0];    // [16384]
    const float* W = (const float*)d_in[1];  // [50400*4096]
    const float* b = (const float*)d_in[2];  // [8*4096]
    float* out  = (float*)d_out;             // [16384*4096]
    float* bsum = (float*)d_ws;              // 4096 floats scratch

    bias_sum_kernel<<<OUT_DIM / 256, 256, 0, stream>>>(b, bsum);
    gather_rows_kernel<<<BLOCKS, THREADS, 0, stream>>>(
        x, (const f4*)W, (const f4*)bsum, (f4*)out);
}